// Round 12
// baseline (420.418 us; speedup 1.0000x reference)
//
#include <hip/hip_runtime.h>
#include <utility>

#define D_DIM 256
#define DV    64               // D in float4 units
#define WID   33
#define CEN   16
#define RSTR  64               // rows per block
#define RW    16               // rows per wave (wave covers ALL 256 cols)
#define WINW  (RW + WID - 1)   // 48 float4 window rows per wave
#define WPAD  36               // LDS weight row stride (16B-aligned)
#define LW_N  (RSTR * WPAD)

// R11 post-mortem: every round's x traffic was dword (256B/instr) with ~8
// loads in flight -> latency*MLP caps read BW at ~2 TB/s (the 104-111us
// plateau). Here one wave = one full row of 64 float4: dwordx4 loads/stores
// (1KB/instr) lift bytes-in-flight 4x. Weights stay in LDS (R10-proven,
// broadcast reads, each b128 now feeds 16 FMAs).

typedef float f32x4 __attribute__((ext_vector_type(4)));

__device__ __forceinline__ f32x4 fma4(f32x4 a, float b, f32x4 c) {
    c[0] = fmaf(a[0], b, c[0]);
    c[1] = fmaf(a[1], b, c[1]);
    c[2] = fmaf(a[2], b, c[2]);
    c[3] = fmaf(a[3], b, c[3]);
    return c;
}

template <size_t... Ts>
__device__ __forceinline__ void load_win(f32x4 (&W)[WINW],
                                         const f32x4* __restrict__ xw,
                                         std::index_sequence<Ts...>) {
    ((W[Ts] = xw[(ptrdiff_t)Ts * DV]), ...);
}

template <size_t... Ts>
__device__ __forceinline__ void load_win_guard(f32x4 (&W)[WINW],
                                               const f32x4* __restrict__ xw,
                                               int base, int N,
                                               std::index_sequence<Ts...>) {
    ((W[Ts] = ((unsigned)(base + (int)Ts) < (unsigned)N)
                  ? xw[(ptrdiff_t)Ts * DV]
                  : (f32x4){0.f, 0.f, 0.f, 0.f}),
     ...);
}

template <int J, size_t... Is>
__device__ __forceinline__ f32x4 dot_row(const f32x4 (&W)[WINW],
                                         const float* __restrict__ lwrow,
                                         std::index_sequence<Is...>) {
    f32x4 acc[2] = {{0.f, 0.f, 0.f, 0.f}, {0.f, 0.f, 0.f, 0.f}};
    ((acc[Is & 1] = fma4(W[J + (int)Is], lwrow[Is], acc[Is & 1])), ...);
    return acc[0] + acc[1];
}

template <size_t... Js>
__device__ __forceinline__ void all_rows(const f32x4 (&W)[WINW],
                                         const float* __restrict__ lwb,
                                         const float* __restrict__ lszb,
                                         f32x4* __restrict__ ob4,
                                         std::index_sequence<Js...>) {
    (([&] {
         const f32x4 s = dot_row<(int)Js>(W, lwb + (int)Js * WPAD,
                                          std::make_index_sequence<WID>{});
         const float inv = __builtin_amdgcn_rcpf(fmaxf(lszb[(int)Js], 1e-6f));
         f32x4 o;
         o[0] = s[0] * inv; o[1] = s[1] * inv;
         o[2] = s[2] * inv; o[3] = s[3] * inv;
         ob4[(ptrdiff_t)Js * DV] = o;
     }()),
     ...);
}

__global__ __launch_bounds__(256, 4) void local_enc_kernel(
    const float* __restrict__ x, const float* __restrict__ sizev,
    const float* __restrict__ sm, float* __restrict__ out, int N) {
    __shared__ __align__(16) float lw[LW_N];   // 64 rows x 36 padded weights
    __shared__ float lsz[RSTR];

    const int tid = threadIdx.x;
    const int b   = blockIdx.y;
    const int n0  = blockIdx.x * RSTR;

    const size_t bN = (size_t)b * (size_t)N;
    const float* __restrict__ smb = sm + bN * WID;

    // stage weights (+sizes) once per block; reads below are broadcasts
#pragma unroll
    for (int k = tid; k < LW_N; k += D_DIM) {     // 9 iterations
        const int r = k / WPAD;
        const int o = k - r * WPAD;
        lw[k] = (o < WID) ? smb[(size_t)(n0 + r) * WID + o] : 0.0f;
    }
    if (tid < RSTR) lsz[tid] = sizev[bN + n0 + tid];
    __syncthreads();

    const int wv   = tid >> 6;          // wave -> 16-row slice
    const int lane = tid & 63;          // lane -> float4 column
    const int nw   = n0 + RW * wv;
    const int base = nw - CEN;

    const f32x4* __restrict__ x4 = (const f32x4*)x;
    const f32x4* __restrict__ xw =
        x4 + ((ptrdiff_t)bN + base) * DV + lane;
    f32x4* __restrict__ ob4 =
        (f32x4*)out + ((ptrdiff_t)bN + nw) * DV + lane;

    const bool interior = (base >= 0) && (base + WINW <= N);

    f32x4 W[WINW];
    if (interior)
        load_win(W, xw, std::make_index_sequence<WINW>{});
    else
        load_win_guard(W, xw, base, N, std::make_index_sequence<WINW>{});

    all_rows(W, lw + (RW * wv) * WPAD, lsz + RW * wv, ob4,
             std::make_index_sequence<RW>{});
}

extern "C" void kernel_launch(void* const* d_in, const int* in_sizes, int n_in,
                              void* d_out, int out_size, void* d_ws, size_t ws_size,
                              hipStream_t stream) {
    const float* x  = (const float*)d_in[0];
    const float* sz = (const float*)d_in[1];
    const float* sm = (const float*)d_in[2];
    float* out = (float*)d_out;

    const int B = 8;
    const int N = 16384;

    dim3 grid(N / RSTR, B, 1);   // 256 x 8 = 2048 blocks
    dim3 block(D_DIM, 1, 1);
    local_enc_kernel<<<grid, block, 0, stream>>>(x, sz, sm, out, N);
}

// Round 13
// 84.916 us; speedup vs baseline: 4.9510x; 4.9510x over previous
//
#include <hip/hip_runtime.h>
#include <utility>

#define D_DIM 256
#define WID   33
#define CEN   16
#define RSTR  32                   // rows per block — no row tail (512*32 = N)
#define WINW  (RSTR + WID - 1)     // 64-value x register window

// R12 post-mortem: f32x4 window = 192 VGPR -> spill (684MB scratch writes).
// R10's real wall: weight broadcast ds_reads saturate the per-CU LDS pipe
// (9 b128/row x 4 slices x 512 rows/CU x 12cy ~= 92us). Fix: distribute
// weights by LANE (one coalesced dword load per row) and share via
// v_readlane (VALU pipe, per-SIMD = 4x aggregate of LDS pipe). No LDS at
// all; weight-row prefetch is plain VMEM, 1 VGPR per row, vmcnt-pipelined.

__device__ __forceinline__ float rdlane(float v, int l) {
    return __uint_as_float(__builtin_amdgcn_readlane(__float_as_uint(v), l));
}

template <size_t... Is>
__device__ __forceinline__ void load_win(float (&W)[WINW],
                                         const float* __restrict__ xb,
                                         int base, std::index_sequence<Is...>) {
    ((W[Is] = xb[(size_t)(base + (int)Is) * D_DIM]), ...);
}

template <size_t... Is>
__device__ __forceinline__ void load_win_guard(float (&W)[WINW],
                                               const float* __restrict__ xb,
                                               int base, int N,
                                               std::index_sequence<Is...>) {
    ((W[Is] = (base + (int)Is >= 0 && base + (int)Is < N)
                  ? xb[(size_t)(base + (int)Is) * D_DIM]
                  : 0.0f),
     ...);
}

// wv[R]: lane i holds sm[n0+R][i] (lanes >= 33 hold a duplicate of tap 32)
template <size_t... Rs>
__device__ __forceinline__ void load_w(float (&wv)[RSTR],
                                       const float* __restrict__ smb,
                                       int n0, int minl,
                                       std::index_sequence<Rs...>) {
    ((wv[Rs] = smb[(size_t)(n0 + (int)Rs) * WID + minl]), ...);
}

template <int R, size_t... Is>
__device__ __forceinline__ float dot_row(const float (&W)[WINW], float wrow,
                                         std::index_sequence<Is...>) {
    float acc[4] = {0.f, 0.f, 0.f, 0.f};
    ((acc[Is & 3] = fmaf(W[R + (int)Is], rdlane(wrow, (int)Is), acc[Is & 3])),
     ...);
    return (acc[0] + acc[1]) + (acc[2] + acc[3]);
}

template <size_t... Rs>
__device__ __forceinline__ void all_rows(const float (&W)[WINW],
                                         const float (&wv)[RSTR], float szv,
                                         float* __restrict__ ob, int n0,
                                         std::index_sequence<Rs...>) {
    (([&] {
         const int n = n0 + (int)Rs;
         const float s =
             dot_row<(int)Rs>(W, wv[(int)Rs], std::make_index_sequence<WID>{});
         const float inv = __builtin_amdgcn_rcpf(
             fmaxf(rdlane(szv, (int)Rs), 1e-6f));
         ob[(size_t)n * D_DIM] = s * inv;
     }()),
     ...);
}

__global__ __launch_bounds__(256, 4) void local_enc_kernel(
    const float* __restrict__ x, const float* __restrict__ sizev,
    const float* __restrict__ sm, float* __restrict__ out, int N) {
    const int tid  = threadIdx.x;
    const int lane = tid & 63;
    const int b    = blockIdx.y;
    const int n0   = blockIdx.x * RSTR;

    const size_t bN = (size_t)b * (size_t)N;
    const float* __restrict__ xb  = x   + bN * D_DIM + tid;
    float*       __restrict__ ob  = out + bN * D_DIM + tid;
    const float* __restrict__ smb = sm    + bN * WID;
    const float* __restrict__ szb = sizev + bN;

    // lane-distributed weight rows + sizes (VMEM dword, coalesced)
    const int minl = (lane < WID) ? lane : (WID - 1);
    float wv[RSTR];
    load_w(wv, smb, n0, minl, std::make_index_sequence<RSTR>{});
    const int szi = n0 + minl;
    const float szv = szb[(szi < N) ? szi : (N - 1)];

    // x register window (R8-proven straight-line structure)
    const int  base     = n0 - CEN;
    const bool interior = (base >= 0) && (base + WINW <= N);

    float W[WINW];
    if (interior)
        load_win(W, xb, base, std::make_index_sequence<WINW>{});
    else
        load_win_guard(W, xb, base, N, std::make_index_sequence<WINW>{});

    all_rows(W, wv, szv, ob, n0, std::make_index_sequence<RSTR>{});
}

extern "C" void kernel_launch(void* const* d_in, const int* in_sizes, int n_in,
                              void* d_out, int out_size, void* d_ws, size_t ws_size,
                              hipStream_t stream) {
    const float* x  = (const float*)d_in[0];
    const float* sz = (const float*)d_in[1];
    const float* sm = (const float*)d_in[2];
    float* out = (float*)d_out;

    const int B = 8;
    const int N = 16384;

    dim3 grid(N / RSTR, B, 1);   // 512 x 8 = 4096 blocks
    dim3 block(D_DIM, 1, 1);
    local_enc_kernel<<<grid, block, 0, stream>>>(x, sz, sm, out, N);
}